// Round 5
// baseline (236.890 us; speedup 1.0000x reference)
//
#include <hip/hip_runtime.h>
#include <hip/hip_bf16.h>

#define NN 256
#define NH 8
#define NB 4
#define NPOS (NB * NN * NN)   // 262144 positions (b,n,m)

typedef float f32x4 __attribute__((ext_vector_type(4)));

// ---------------------------------------------------------------------------
// Kernel 1: attn[p][h] = sigmoid( dot(concat(q[p],k[p]), W[:,h]) + b[h] )
// Pure-streaming loads (m13 pattern: lane i <- row + 16B*i, 1KB/inst) into
// registers, then ds_write_b128 into a wave-private LDS double buffer
// (T14 issue-early/write-late: next tile's loads issue before current tile's
// compute, so HBM latency hides under FMA+LDS work). No barriers, no DMA.
// lane=(g,h): g = 64-float chunk of ft[512], h = head. LDS reads XOR-swizzled
// (step s reads element s^g) -> zero bank conflicts (verified R4); W coeffs
// pre-permuted so wreg index is compile-time.
// ---------------------------------------------------------------------------
__global__ __launch_bounds__(256) void attn_kernel(
    const float* __restrict__ q, const float* __restrict__ k,
    const float* __restrict__ W, const float* __restrict__ bias,
    float* __restrict__ attn)
{
    __shared__ __align__(256) char lds[32768];   // 4 waves x 2 buf x 4KB
    const int tid = threadIdx.x;
    const int lane = tid & 63;
    const int wid = tid >> 6;
    const int h = lane & 7;
    const int g = lane >> 3;          // 0..7

    // wreg[4*s+c] = W coeff for data element e = s^g of this lane's chunk
    float wreg[64];
#pragma unroll
    for (int s = 0; s < 16; ++s) {
        const int e = s ^ g;          // s<16, g<8 -> e<16
#pragma unroll
        for (int c = 0; c < 4; ++c)
            wreg[4 * s + c] = W[(size_t)((g << 6) + (e << 2) + c) * NH + h];
    }
    const float bb = bias[h];

    char* myLds = &lds[wid * 8192];
    const int gwave = blockIdx.x * 4 + wid;
    const int nwaves = gridDim.x * 4;          // 16384
    const int stride = nwaves * 2;             // 32768 positions per round

    const size_t laneOff = (size_t)lane * 4;   // float offset (16B per lane)
    const int qkByte = (g < 4) ? 0 : 2048;
    const int chunkByte = (g & 3) * 256;

    const int p0 = gwave * 2;

    // prologue: load tile p0 to regs, write buffer 0
    {
        f32x4 r0 = *(const f32x4*)(q + (size_t)p0 * 256 + laneOff);
        f32x4 r1 = *(const f32x4*)(q + (size_t)(p0 + 1) * 256 + laneOff);
        f32x4 r2 = *(const f32x4*)(k + (size_t)p0 * 256 + laneOff);
        f32x4 r3 = *(const f32x4*)(k + (size_t)(p0 + 1) * 256 + laneOff);
        char* b0 = myLds;
        *(f32x4*)(b0 + 0    + lane * 16) = r0;
        *(f32x4*)(b0 + 1024 + lane * 16) = r1;
        *(f32x4*)(b0 + 2048 + lane * 16) = r2;
        *(f32x4*)(b0 + 3072 + lane * 16) = r3;
    }

    int buf = 0;
    for (int p = p0; p < NPOS; p += stride) {
        const int pn = p + stride;
        f32x4 n0, n1, n2, n3;
        const bool hasNext = (pn < NPOS);
        if (hasNext) {   // issue next tile's loads EARLY (hide under compute)
            n0 = *(const f32x4*)(q + (size_t)pn * 256 + laneOff);
            n1 = *(const f32x4*)(q + (size_t)(pn + 1) * 256 + laneOff);
            n2 = *(const f32x4*)(k + (size_t)pn * 256 + laneOff);
            n3 = *(const f32x4*)(k + (size_t)(pn + 1) * 256 + laneOff);
        }

        // compute current tile from LDS buffer `buf`
        const uintptr_t A0 =
            (uintptr_t)(myLds + (buf << 12) + qkByte + chunkByte) + (g << 4);
        float acc0 = 0.f, acc1 = 0.f;
#pragma unroll
        for (int s = 0; s < 16; ++s) {
            const float* f0 = (const float*)(A0 ^ (uintptr_t)(s << 4));
            f32x4 v0 = *(const f32x4*)(f0);         // pos p   (ds_read_b128)
            f32x4 v1 = *(const f32x4*)(f0 + 256);   // pos p+1 (+1024B imm)
            acc0 += v0.x * wreg[4 * s + 0];
            acc0 += v0.y * wreg[4 * s + 1];
            acc0 += v0.z * wreg[4 * s + 2];
            acc0 += v0.w * wreg[4 * s + 3];
            acc1 += v1.x * wreg[4 * s + 0];
            acc1 += v1.y * wreg[4 * s + 1];
            acc1 += v1.z * wreg[4 * s + 2];
            acc1 += v1.w * wreg[4 * s + 3];
        }
        acc0 += __shfl_xor(acc0, 8);
        acc0 += __shfl_xor(acc0, 16);
        acc0 += __shfl_xor(acc0, 32);
        acc1 += __shfl_xor(acc1, 8);
        acc1 += __shfl_xor(acc1, 16);
        acc1 += __shfl_xor(acc1, 32);
        if (lane < 8) {
            attn[(size_t)p * NH + lane]       = 1.f / (1.f + __expf(-(acc0 + bb)));
            attn[(size_t)(p + 1) * NH + lane] = 1.f / (1.f + __expf(-(acc1 + bb)));
        }

        if (hasNext) {   // write-late: stage next tile into the other buffer
            char* nb = myLds + ((buf ^ 1) << 12);
            *(f32x4*)(nb + 0    + lane * 16) = n0;
            *(f32x4*)(nb + 1024 + lane * 16) = n1;
            *(f32x4*)(nb + 2048 + lane * 16) = n2;
            *(f32x4*)(nb + 3072 + lane * 16) = n3;
        }
        buf ^= 1;
    }
}

// ---------------------------------------------------------------------------
// Kernel 2: dim2_mask union of top-k / bottom-k indices (exact rank count,
// matches jax.lax.top_k stable tie-breaking). Register-accumulated selection,
// ballot + 2 atomicOr per wave; 64 publisher blocks seed the mask per-task;
// everyone early-exits on full mask via volatile loads (monotonic bits =>
// stale reads are safe).
// ---------------------------------------------------------------------------
__global__ __launch_bounds__(256) void topk_kernel(
    const float* __restrict__ attn, const float* __restrict__ m1,
    const float* __restrict__ m2, unsigned int* __restrict__ maskw)
{
    __shared__ __align__(16) float a[NN];
    __shared__ int snotfull;
    const int tid = threadIdx.x;
    const int T = 2 * NB * NN * NH;   // 16384 tasks
    const bool publisher = (blockIdx.x < 64);
    const volatile unsigned int* vmask = maskw;
    bool selAcc = false;
    bool broke = false;

    for (int t = blockIdx.x; t < T; t += gridDim.x) {
        if (t != (int)blockIdx.x) {
            if (tid == 0) snotfull = 0;
            __syncthreads();
            if (tid < 8 && vmask[tid] != 0xFFFFFFFFu) snotfull = 1;
            __syncthreads();
            if (!snotfull) { broke = true; break; }
        }

        const int variant = t >> 13;
        const int r = t & 8191;
        const int h = r & 7;
        const int n = (r >> 3) & 255;
        const int b = r >> 11;
        const size_t rowBase = ((size_t)(b * NN + n)) * NN;
        const float* mk = variant ? m2 : m1;
        const int kt = variant ? 128 : 64;
        const int kb = 64;

        a[tid] = attn[(rowBase + tid) * NH + h] * mk[rowBase + tid];
        __syncthreads();

        const float av = a[tid];
        int gt = 0, lt = 0, el = 0;
#pragma unroll 8
        for (int u4 = 0; u4 < NN / 4; ++u4) {
            const f32x4 w = *reinterpret_cast<const f32x4*>(&a[u4 * 4]);
            const int u = u4 * 4;
            gt += (w.x > av) + (w.y > av) + (w.z > av) + (w.w > av);
            lt += (w.x < av) + (w.y < av) + (w.z < av) + (w.w < av);
            el += ((w.x == av) & (u + 0 < tid)) + ((w.y == av) & (u + 1 < tid))
                + ((w.z == av) & (u + 2 < tid)) + ((w.w == av) & (u + 3 < tid));
        }
        const bool sel = ((gt + el) < kt) || ((lt + el) < kb);
        selAcc |= sel;

        if (publisher) {
            const unsigned long long bal = __ballot(sel);
            if ((tid & 63) == 0) {
                const int w = tid >> 6;
                atomicOr(&maskw[w * 2 + 0], (unsigned int)(bal & 0xFFFFFFFFull));
                atomicOr(&maskw[w * 2 + 1], (unsigned int)(bal >> 32));
            }
        }
        __syncthreads();
    }

    if (!broke && !publisher) {
        const unsigned long long bal = __ballot(selAcc);
        if ((tid & 63) == 0) {
            const int w = tid >> 6;
            atomicOr(&maskw[w * 2 + 0], (unsigned int)(bal & 0xFFFFFFFFull));
            atomicOr(&maskw[w * 2 + 1], (unsigned int)(bal >> 32));
        }
    }
}

// ---------------------------------------------------------------------------
// Kernel 3: out *= (m1+m2) * dim2_mask[m], in place, float4 over H.
// ---------------------------------------------------------------------------
__global__ __launch_bounds__(256) void finalize_kernel(
    float* __restrict__ out, const float* __restrict__ m1,
    const float* __restrict__ m2, const unsigned int* __restrict__ maskw)
{
    const int total = NPOS * 2;       // float4 units (H=8 -> 2 per position)
    for (int i4 = blockIdx.x * blockDim.x + threadIdx.x; i4 < total;
         i4 += gridDim.x * blockDim.x) {
        const int m = (i4 >> 1) & 255;
        const int bn = i4 >> 9;
        const float bit = ((maskw[m >> 5] >> (m & 31)) & 1u) ? 1.f : 0.f;
        const size_t mi = (size_t)bn * NN + m;
        const float scale = (m1[mi] + m2[mi]) * bit;
        f32x4 v = reinterpret_cast<f32x4*>(out)[i4];
        v.x *= scale; v.y *= scale; v.z *= scale; v.w *= scale;
        reinterpret_cast<f32x4*>(out)[i4] = v;
    }
}

__global__ void init_kernel(unsigned int* maskw)
{
    if (threadIdx.x < 8) maskw[threadIdx.x] = 0u;
}

extern "C" void kernel_launch(void* const* d_in, const int* in_sizes, int n_in,
                              void* d_out, int out_size, void* d_ws, size_t ws_size,
                              hipStream_t stream) {
    const float* q    = (const float*)d_in[0];
    const float* kk   = (const float*)d_in[1];
    const float* m1   = (const float*)d_in[2];
    const float* m2   = (const float*)d_in[3];
    const float* W    = (const float*)d_in[4];
    const float* bias = (const float*)d_in[5];
    float* out = (float*)d_out;

    unsigned int* maskw = (unsigned int*)d_ws;

    hipLaunchKernelGGL(init_kernel, dim3(1), dim3(64), 0, stream, maskw);
    // 4096 blocks * 4 waves = 16384 waves; stride 32768 -> 8 tiles/wave
    hipLaunchKernelGGL(attn_kernel, dim3(4096), dim3(256), 0, stream,
                       q, kk, W, bias, out);
    hipLaunchKernelGGL(topk_kernel, dim3(1024), dim3(256), 0, stream,
                       out, m1, m2, maskw);
    hipLaunchKernelGGL(finalize_kernel, dim3(2048), dim3(256), 0, stream,
                       out, m1, m2, maskw);
}

// Round 6
// 175.868 us; speedup vs baseline: 1.3470x; 1.3470x over previous
//
#include <hip/hip_runtime.h>
#include <hip/hip_bf16.h>

#define NN 256
#define NH 8
#define NB 4
#define NPOS (NB * NN * NN)   // 262144 positions (b,n,m)

typedef float f32x4 __attribute__((ext_vector_type(4)));

// ---------------------------------------------------------------------------
// Kernel 1: attn[p][h] = sigmoid( dot(concat(q[p],k[p]), W[:,h]) + b[h] )
// NO LDS data path (R4/R5 showed identical 223us with data in L3 vs HBM =>
// on-chip LDS pipe / serialization bound, not memory). Lane l owns ft dims
// [4l..4l+3] of q and k; W block (8 dims x 8 heads = 64 coeffs) in registers.
// Loads stay m13-style coalesced (lane i <- row + 16B*i, 1KB/instr).
// Reduction: xor 1/2/4 on 8 accs (DPP-cheap), select head c=lane&7, then
// xor 8/16/32 on one scalar. ~3 LDS-pipe ops/pos instead of 36.
// ---------------------------------------------------------------------------
__global__ __launch_bounds__(256, 4) void attn_kernel(
    const float* __restrict__ q, const float* __restrict__ k,
    const float* __restrict__ W, const float* __restrict__ bias,
    float* __restrict__ attn)
{
    const int tid = threadIdx.x;
    const int lane = tid & 63;
    const int c = lane & 7;

    // per-lane W blocks: q-part rows 4*lane..4*lane+3, k-part rows 256+4*lane..
    // A = heads 0..3, B = heads 4..7
    f32x4 wqA[4], wqB[4], wkA[4], wkB[4];
#pragma unroll
    for (int cc = 0; cc < 4; ++cc) {
        const float* wr = W + (size_t)(4 * lane + cc) * NH;
        wqA[cc] = *(const f32x4*)(wr);
        wqB[cc] = *(const f32x4*)(wr + 4);
        const float* wr2 = W + (size_t)(256 + 4 * lane + cc) * NH;
        wkA[cc] = *(const f32x4*)(wr2);
        wkB[cc] = *(const f32x4*)(wr2 + 4);
    }
    const float bb = bias[c];

    const int gwave = blockIdx.x * (blockDim.x >> 6) + (tid >> 6);
    const int nwaves = gridDim.x * (blockDim.x >> 6);  // 16384
    const size_t laneF = (size_t)lane * 4;

    int p = gwave;
    f32x4 qc4 = *(const f32x4*)(q + (size_t)p * 256 + laneF);
    f32x4 kc4 = *(const f32x4*)(k + (size_t)p * 256 + laneF);

    while (p < NPOS) {
        const int pn = p + nwaves;
        f32x4 qn4, kn4;
        const bool hasNext = (pn < NPOS);
        if (hasNext) {   // prefetch next position (hide HBM under compute)
            qn4 = *(const f32x4*)(q + (size_t)pn * 256 + laneF);
            kn4 = *(const f32x4*)(k + (size_t)pn * 256 + laneF);
        }

        // 64 FMAs: acc[h] over this lane's 8 dims
        f32x4 accA, accB;
        accA  = wqA[0] * qc4.x;  accB  = wqB[0] * qc4.x;
        accA += wqA[1] * qc4.y;  accB += wqB[1] * qc4.y;
        accA += wqA[2] * qc4.z;  accB += wqB[2] * qc4.z;
        accA += wqA[3] * qc4.w;  accB += wqB[3] * qc4.w;
        accA += wkA[0] * kc4.x;  accB += wkB[0] * kc4.x;
        accA += wkA[1] * kc4.y;  accB += wkB[1] * kc4.y;
        accA += wkA[2] * kc4.z;  accB += wkB[2] * kc4.z;
        accA += wkA[3] * kc4.w;  accB += wkB[3] * kc4.w;

        // phase 1: reduce over lanes within group of 8 (xor 1,2,4; DPP-cheap)
#pragma unroll
        for (int d = 1; d <= 4; d <<= 1) {
            accA.x += __shfl_xor(accA.x, d);
            accA.y += __shfl_xor(accA.y, d);
            accA.z += __shfl_xor(accA.z, d);
            accA.w += __shfl_xor(accA.w, d);
            accB.x += __shfl_xor(accB.x, d);
            accB.y += __shfl_xor(accB.y, d);
            accB.z += __shfl_xor(accB.z, d);
            accB.w += __shfl_xor(accB.w, d);
        }

        // select own head c = lane&7 (compile-time cndmask chain)
        float my = accA.x;
        my = (c == 1) ? accA.y : my;
        my = (c == 2) ? accA.z : my;
        my = (c == 3) ? accA.w : my;
        my = (c == 4) ? accB.x : my;
        my = (c == 5) ? accB.y : my;
        my = (c == 6) ? accB.z : my;
        my = (c == 7) ? accB.w : my;

        // phase 2: reduce across the 8 lane-groups (one scalar per lane)
        my += __shfl_xor(my, 8);
        my += __shfl_xor(my, 16);
        my += __shfl_xor(my, 32);

        const float s = 1.f / (1.f + __expf(-(my + bb)));
        if (lane < 8) attn[(size_t)p * NH + lane] = s;

        qc4 = qn4; kc4 = kn4;
        p = pn;
    }
}

// ---------------------------------------------------------------------------
// Kernel 2: dim2_mask union of top-k / bottom-k indices (exact rank count,
// matches jax.lax.top_k stable tie-breaking). Register-accumulated selection,
// ballot + 2 atomicOr per wave; 64 publisher blocks seed the mask per-task;
// everyone early-exits on full mask via volatile loads (monotonic bits =>
// stale reads are safe).
// ---------------------------------------------------------------------------
__global__ __launch_bounds__(256) void topk_kernel(
    const float* __restrict__ attn, const float* __restrict__ m1,
    const float* __restrict__ m2, unsigned int* __restrict__ maskw)
{
    __shared__ __align__(16) float a[NN];
    __shared__ int snotfull;
    const int tid = threadIdx.x;
    const int T = 2 * NB * NN * NH;   // 16384 tasks
    const bool publisher = (blockIdx.x < 64);
    const volatile unsigned int* vmask = maskw;
    bool selAcc = false;
    bool broke = false;

    for (int t = blockIdx.x; t < T; t += gridDim.x) {
        if (t != (int)blockIdx.x) {
            if (tid == 0) snotfull = 0;
            __syncthreads();
            if (tid < 8 && vmask[tid] != 0xFFFFFFFFu) snotfull = 1;
            __syncthreads();
            if (!snotfull) { broke = true; break; }
        }

        const int variant = t >> 13;
        const int r = t & 8191;
        const int h = r & 7;
        const int n = (r >> 3) & 255;
        const int b = r >> 11;
        const size_t rowBase = ((size_t)(b * NN + n)) * NN;
        const float* mk = variant ? m2 : m1;
        const int kt = variant ? 128 : 64;
        const int kb = 64;

        a[tid] = attn[(rowBase + tid) * NH + h] * mk[rowBase + tid];
        __syncthreads();

        const float av = a[tid];
        int gt = 0, lt = 0, el = 0;
#pragma unroll 8
        for (int u4 = 0; u4 < NN / 4; ++u4) {
            const f32x4 w = *reinterpret_cast<const f32x4*>(&a[u4 * 4]);
            const int u = u4 * 4;
            gt += (w.x > av) + (w.y > av) + (w.z > av) + (w.w > av);
            lt += (w.x < av) + (w.y < av) + (w.z < av) + (w.w < av);
            el += ((w.x == av) & (u + 0 < tid)) + ((w.y == av) & (u + 1 < tid))
                + ((w.z == av) & (u + 2 < tid)) + ((w.w == av) & (u + 3 < tid));
        }
        const bool sel = ((gt + el) < kt) || ((lt + el) < kb);
        selAcc |= sel;

        if (publisher) {
            const unsigned long long bal = __ballot(sel);
            if ((tid & 63) == 0) {
                const int w = tid >> 6;
                atomicOr(&maskw[w * 2 + 0], (unsigned int)(bal & 0xFFFFFFFFull));
                atomicOr(&maskw[w * 2 + 1], (unsigned int)(bal >> 32));
            }
        }
        __syncthreads();
    }

    if (!broke && !publisher) {
        const unsigned long long bal = __ballot(selAcc);
        if ((tid & 63) == 0) {
            const int w = tid >> 6;
            atomicOr(&maskw[w * 2 + 0], (unsigned int)(bal & 0xFFFFFFFFull));
            atomicOr(&maskw[w * 2 + 1], (unsigned int)(bal >> 32));
        }
    }
}

// ---------------------------------------------------------------------------
// Kernel 3: out *= (m1+m2) * dim2_mask[m], in place, float4 over H.
// ---------------------------------------------------------------------------
__global__ __launch_bounds__(256) void finalize_kernel(
    float* __restrict__ out, const float* __restrict__ m1,
    const float* __restrict__ m2, const unsigned int* __restrict__ maskw)
{
    const int total = NPOS * 2;       // float4 units (H=8 -> 2 per position)
    for (int i4 = blockIdx.x * blockDim.x + threadIdx.x; i4 < total;
         i4 += gridDim.x * blockDim.x) {
        const int m = (i4 >> 1) & 255;
        const int bn = i4 >> 9;
        const float bit = ((maskw[m >> 5] >> (m & 31)) & 1u) ? 1.f : 0.f;
        const size_t mi = (size_t)bn * NN + m;
        const float scale = (m1[mi] + m2[mi]) * bit;
        f32x4 v = reinterpret_cast<f32x4*>(out)[i4];
        v.x *= scale; v.y *= scale; v.z *= scale; v.w *= scale;
        reinterpret_cast<f32x4*>(out)[i4] = v;
    }
}

__global__ void init_kernel(unsigned int* maskw)
{
    if (threadIdx.x < 8) maskw[threadIdx.x] = 0u;
}

extern "C" void kernel_launch(void* const* d_in, const int* in_sizes, int n_in,
                              void* d_out, int out_size, void* d_ws, size_t ws_size,
                              hipStream_t stream) {
    const float* q    = (const float*)d_in[0];
    const float* kk   = (const float*)d_in[1];
    const float* m1   = (const float*)d_in[2];
    const float* m2   = (const float*)d_in[3];
    const float* W    = (const float*)d_in[4];
    const float* bias = (const float*)d_in[5];
    float* out = (float*)d_out;

    unsigned int* maskw = (unsigned int*)d_ws;

    hipLaunchKernelGGL(init_kernel, dim3(1), dim3(64), 0, stream, maskw);
    // 4096 blocks * 4 waves = 16384 waves -> exactly 16 positions per wave
    hipLaunchKernelGGL(attn_kernel, dim3(4096), dim3(256), 0, stream,
                       q, kk, W, bias, out);
    hipLaunchKernelGGL(topk_kernel, dim3(1024), dim3(256), 0, stream,
                       out, m1, m2, maskw);
    hipLaunchKernelGGL(finalize_kernel, dim3(2048), dim3(256), 0, stream,
                       out, m1, m2, maskw);
}

// Round 7
// 155.275 us; speedup vs baseline: 1.5256x; 1.1326x over previous
//
#include <hip/hip_runtime.h>
#include <hip/hip_bf16.h>

#define NN 256
#define NH 8
#define NB 4
#define NPOS (NB * NN * NN)   // 262144 positions (b,n,m)

typedef float f32x4 __attribute__((ext_vector_type(4)));

// ---------------------------------------------------------------------------
// Kernel 1: attn[p][h] = sigmoid( dot(concat(q[p],k[p]), W[:,h]) + b[h] )
// R6 evidence: latency-bound (VALUBusy 25%, warm==cold duration). Fix: batch
// 4 positions per step, double-buffered register pipeline (issue next batch's
// 8x1KB loads before computing current batch -> 8KB always in flight/wave,
// waits amortized over ~1000cy of compute). Lane l owns ft dims [4l..4l+3];
// W block in 64 VGPRs; no LDS. Packed epilogue: lanes 0..31 store 4 positions
// x 8 heads = 128B contiguous per batch.
// ---------------------------------------------------------------------------
__device__ __forceinline__ float posval(
    const f32x4 qv, const f32x4 kv,
    const f32x4* __restrict__ wqA, const f32x4* __restrict__ wqB,
    const f32x4* __restrict__ wkA, const f32x4* __restrict__ wkB,
    const int c)
{
    f32x4 accA, accB;
    accA  = wqA[0] * qv.x;  accB  = wqB[0] * qv.x;
    accA += wqA[1] * qv.y;  accB += wqB[1] * qv.y;
    accA += wqA[2] * qv.z;  accB += wqB[2] * qv.z;
    accA += wqA[3] * qv.w;  accB += wqB[3] * qv.w;
    accA += wkA[0] * kv.x;  accB += wkB[0] * kv.x;
    accA += wkA[1] * kv.y;  accB += wkB[1] * kv.y;
    accA += wkA[2] * kv.z;  accB += wkB[2] * kv.z;
    accA += wkA[3] * kv.w;  accB += wkB[3] * kv.w;

#pragma unroll
    for (int d = 1; d <= 4; d <<= 1) {
        accA.x += __shfl_xor(accA.x, d);
        accA.y += __shfl_xor(accA.y, d);
        accA.z += __shfl_xor(accA.z, d);
        accA.w += __shfl_xor(accA.w, d);
        accB.x += __shfl_xor(accB.x, d);
        accB.y += __shfl_xor(accB.y, d);
        accB.z += __shfl_xor(accB.z, d);
        accB.w += __shfl_xor(accB.w, d);
    }
    float my = accA.x;
    my = (c == 1) ? accA.y : my;
    my = (c == 2) ? accA.z : my;
    my = (c == 3) ? accA.w : my;
    my = (c == 4) ? accB.x : my;
    my = (c == 5) ? accB.y : my;
    my = (c == 6) ? accB.z : my;
    my = (c == 7) ? accB.w : my;
    my += __shfl_xor(my, 8);
    my += __shfl_xor(my, 16);
    my += __shfl_xor(my, 32);
    return my;
}

#define LOADB(dq, dk, pb)                                                   \
    _Pragma("unroll")                                                       \
    for (int i = 0; i < 4; ++i) {                                           \
        dq[i] = *(const f32x4*)(q + (size_t)((pb) + i) * 256 + laneF);      \
        dk[i] = *(const f32x4*)(k + (size_t)((pb) + i) * 256 + laneF);      \
    }

#define COMPUTEB(sq, sk, pb)                                                \
    {                                                                       \
        const float m0 = posval(sq[0], sk[0], wqA, wqB, wkA, wkB, c);       \
        const float m1 = posval(sq[1], sk[1], wqA, wqB, wkA, wkB, c);       \
        const float m2 = posval(sq[2], sk[2], wqA, wqB, wkA, wkB, c);       \
        const float m3 = posval(sq[3], sk[3], wqA, wqB, wkA, wkB, c);       \
        float v = m0;                                                       \
        v = (g2 == 1) ? m1 : v;                                             \
        v = (g2 == 2) ? m2 : v;                                             \
        v = (g2 == 3) ? m3 : v;                                             \
        v = 1.f / (1.f + __expf(-(v + bb)));                                \
        if (lane < 32) attn[(size_t)(pb) * NH + lane] = v;                  \
    }

__global__ __launch_bounds__(256, 3) void attn_kernel(
    const float* __restrict__ q, const float* __restrict__ k,
    const float* __restrict__ W, const float* __restrict__ bias,
    float* __restrict__ attn)
{
    const int tid = threadIdx.x;
    const int lane = tid & 63;
    const int c = lane & 7;
    const int g2 = (lane >> 3) & 3;    // batch-position select for packed store

    f32x4 wqA[4], wqB[4], wkA[4], wkB[4];
#pragma unroll
    for (int cc = 0; cc < 4; ++cc) {
        const float* wr = W + (size_t)(4 * lane + cc) * NH;
        wqA[cc] = *(const f32x4*)(wr);
        wqB[cc] = *(const f32x4*)(wr + 4);
        const float* wr2 = W + (size_t)(256 + 4 * lane + cc) * NH;
        wkA[cc] = *(const f32x4*)(wr2);
        wkB[cc] = *(const f32x4*)(wr2 + 4);
    }
    const float bb = bias[c];

    const int gwave = blockIdx.x * (blockDim.x >> 6) + (tid >> 6);
    const size_t laneF = (size_t)lane * 4;

    // 8192 waves x 32 contiguous positions each = NPOS exactly
    int pb = gwave * 32;

    f32x4 qA[4], kA[4], qB[4], kB[4];
    LOADB(qA, kA, pb);
#pragma unroll
    for (int b = 0; b < 8; ++b) {
        if ((b & 1) == 0) {
            if (b < 7) LOADB(qB, kB, pb + 4);
            COMPUTEB(qA, kA, pb);
        } else {
            if (b < 7) LOADB(qA, kA, pb + 4);
            COMPUTEB(qB, kB, pb);
        }
        pb += 4;
    }
}

// ---------------------------------------------------------------------------
// Kernel 2: dim2_mask union of top-k / bottom-k indices (exact rank count,
// matches jax.lax.top_k stable tie-breaking). Register-accumulated selection,
// ballot + 2 atomicOr per wave; 64 publisher blocks seed the mask per-task;
// everyone early-exits on full mask via volatile loads (monotonic bits =>
// stale reads are safe).
// ---------------------------------------------------------------------------
__global__ __launch_bounds__(256) void topk_kernel(
    const float* __restrict__ attn, const float* __restrict__ m1,
    const float* __restrict__ m2, unsigned int* __restrict__ maskw)
{
    __shared__ __align__(16) float a[NN];
    __shared__ int snotfull;
    const int tid = threadIdx.x;
    const int T = 2 * NB * NN * NH;   // 16384 tasks
    const bool publisher = (blockIdx.x < 64);
    const volatile unsigned int* vmask = maskw;
    bool selAcc = false;
    bool broke = false;

    for (int t = blockIdx.x; t < T; t += gridDim.x) {
        if (t != (int)blockIdx.x) {
            if (tid == 0) snotfull = 0;
            __syncthreads();
            if (tid < 8 && vmask[tid] != 0xFFFFFFFFu) snotfull = 1;
            __syncthreads();
            if (!snotfull) { broke = true; break; }
        }

        const int variant = t >> 13;
        const int r = t & 8191;
        const int h = r & 7;
        const int n = (r >> 3) & 255;
        const int b = r >> 11;
        const size_t rowBase = ((size_t)(b * NN + n)) * NN;
        const float* mk = variant ? m2 : m1;
        const int kt = variant ? 128 : 64;
        const int kb = 64;

        a[tid] = attn[(rowBase + tid) * NH + h] * mk[rowBase + tid];
        __syncthreads();

        const float av = a[tid];
        int gt = 0, lt = 0, el = 0;
#pragma unroll 8
        for (int u4 = 0; u4 < NN / 4; ++u4) {
            const f32x4 w = *reinterpret_cast<const f32x4*>(&a[u4 * 4]);
            const int u = u4 * 4;
            gt += (w.x > av) + (w.y > av) + (w.z > av) + (w.w > av);
            lt += (w.x < av) + (w.y < av) + (w.z < av) + (w.w < av);
            el += ((w.x == av) & (u + 0 < tid)) + ((w.y == av) & (u + 1 < tid))
                + ((w.z == av) & (u + 2 < tid)) + ((w.w == av) & (u + 3 < tid));
        }
        const bool sel = ((gt + el) < kt) || ((lt + el) < kb);
        selAcc |= sel;

        if (publisher) {
            const unsigned long long bal = __ballot(sel);
            if ((tid & 63) == 0) {
                const int w = tid >> 6;
                atomicOr(&maskw[w * 2 + 0], (unsigned int)(bal & 0xFFFFFFFFull));
                atomicOr(&maskw[w * 2 + 1], (unsigned int)(bal >> 32));
            }
        }
        __syncthreads();
    }

    if (!broke && !publisher) {
        const unsigned long long bal = __ballot(selAcc);
        if ((tid & 63) == 0) {
            const int w = tid >> 6;
            atomicOr(&maskw[w * 2 + 0], (unsigned int)(bal & 0xFFFFFFFFull));
            atomicOr(&maskw[w * 2 + 1], (unsigned int)(bal >> 32));
        }
    }
}

// ---------------------------------------------------------------------------
// Kernel 3: out *= (m1+m2) * dim2_mask[m], in place, float4 over H.
// ---------------------------------------------------------------------------
__global__ __launch_bounds__(256) void finalize_kernel(
    float* __restrict__ out, const float* __restrict__ m1,
    const float* __restrict__ m2, const unsigned int* __restrict__ maskw)
{
    const int total = NPOS * 2;       // float4 units (H=8 -> 2 per position)
    for (int i4 = blockIdx.x * blockDim.x + threadIdx.x; i4 < total;
         i4 += gridDim.x * blockDim.x) {
        const int m = (i4 >> 1) & 255;
        const int bn = i4 >> 9;
        const float bit = ((maskw[m >> 5] >> (m & 31)) & 1u) ? 1.f : 0.f;
        const size_t mi = (size_t)bn * NN + m;
        const float scale = (m1[mi] + m2[mi]) * bit;
        f32x4 v = reinterpret_cast<f32x4*>(out)[i4];
        v.x *= scale; v.y *= scale; v.z *= scale; v.w *= scale;
        reinterpret_cast<f32x4*>(out)[i4] = v;
    }
}

__global__ void init_kernel(unsigned int* maskw)
{
    if (threadIdx.x < 8) maskw[threadIdx.x] = 0u;
}

extern "C" void kernel_launch(void* const* d_in, const int* in_sizes, int n_in,
                              void* d_out, int out_size, void* d_ws, size_t ws_size,
                              hipStream_t stream) {
    const float* q    = (const float*)d_in[0];
    const float* kk   = (const float*)d_in[1];
    const float* m1   = (const float*)d_in[2];
    const float* m2   = (const float*)d_in[3];
    const float* W    = (const float*)d_in[4];
    const float* bias = (const float*)d_in[5];
    float* out = (float*)d_out;

    unsigned int* maskw = (unsigned int*)d_ws;

    hipLaunchKernelGGL(init_kernel, dim3(1), dim3(64), 0, stream, maskw);
    // 2048 blocks * 4 waves = 8192 waves * 32 positions = NPOS exactly
    hipLaunchKernelGGL(attn_kernel, dim3(2048), dim3(256), 0, stream,
                       q, kk, W, bias, out);
    hipLaunchKernelGGL(topk_kernel, dim3(1024), dim3(256), 0, stream,
                       out, m1, m2, maskw);
    hipLaunchKernelGGL(finalize_kernel, dim3(2048), dim3(256), 0, stream,
                       out, m1, m2, maskw);
}